// Round 5
// baseline (924.172 us; speedup 1.0000x reference)
//
#include <hip/hip_runtime.h>
#include <math.h>

// Problem constants (fixed by the reference)
#define B_SZ 2
#define L_SEQ 4096
#define D_MODEL 1024
#define D_INNER 2048
#define D_STATE 64
#define DT_RANK 128
#define BL (B_SZ * L_SEQ)          // 8192 tokens

#define AS1 __attribute__((address_space(1)))
#define AS3 __attribute__((address_space(3)))

typedef __attribute__((ext_vector_type(8))) short bf16x8_t;  // 8 bf16 = 4 VGPRs
typedef __attribute__((ext_vector_type(4))) float f32x4_t;

__device__ __forceinline__ unsigned short f2bf(float f) {
    unsigned int u = __float_as_uint(f);
    u = (u + 0x7FFFu + ((u >> 16) & 1u)) >> 16;   // RNE
    return (unsigned short)u;
}
__device__ __forceinline__ float bf2f(unsigned short h) {
    return __uint_as_float(((unsigned int)h) << 16);
}

// ---------------------------------------------------------------------------
// fp32 -> bf16 bulk convert (n4 = count of float4 groups)
// ---------------------------------------------------------------------------
__global__ __launch_bounds__(256) void cvt_f32_bf16(
    const float* __restrict__ in, unsigned short* __restrict__ out, int n4)
{
    int i = blockIdx.x * 256 + threadIdx.x;
    if (i >= n4) return;
    float4 v = ((const float4*)in)[i];
    ushort4 o;
    o.x = f2bf(v.x); o.y = f2bf(v.y); o.z = f2bf(v.z); o.w = f2bf(v.w);
    ((ushort4*)out)[i] = o;
}

// xdbl[:, :128] (fp32, row stride 256) -> packed bf16 [8192][128]
__global__ __launch_bounds__(256) void cvt_dtpart(
    const float* __restrict__ xdbl, unsigned short* __restrict__ out)
{
    int i = blockIdx.x * 256 + threadIdx.x;   // 0 .. 8192*32-1
    int m = i >> 5, c = i & 31;
    float4 v = *(const float4*)(xdbl + (size_t)m * 256 + c * 4);
    ushort4 o;
    o.x = f2bf(v.x); o.y = f2bf(v.y); o.z = f2bf(v.z); o.w = f2bf(v.w);
    ((ushort4*)(out))[(size_t)m * 32 + c] = o;
}

// ---------------------------------------------------------------------------
// bf16 MFMA GEMM: C[m][n] = act( sum_k A[m][k]*B[n][k] [+ bias[m]] )
// A: M x K bf16 row-major (lda), B: N x K bf16 row-major (ldb), C fp32 (ldc).
// act: 0 none, 1 softplus with bias indexed by ROW m, 2 silu.
// Tile 128x128, BK=32, 256 threads = 4 waves (2x2 of 64x64 per wave).
// ---------------------------------------------------------------------------
__global__ __launch_bounds__(256) void gemm_bf16(
    const unsigned short* __restrict__ A, int lda,
    const unsigned short* __restrict__ B, int ldb,
    float* __restrict__ C, int ldc, int K,
    const float* __restrict__ bias, int act)
{
    __shared__ unsigned short As[128 * 32];   // [row][k] linear, no pad
    __shared__ unsigned short Bs[128 * 32];

    const int tid = threadIdx.x;
    const int w = tid >> 6, lane = tid & 63;
    const int bm = blockIdx.y * 128, bn = blockIdx.x * 128;
    const int wm = (w & 1) * 64, wn = (w >> 1) * 64;

    f32x4_t acc[4][4];
#pragma unroll
    for (int i = 0; i < 4; ++i)
#pragma unroll
        for (int j = 0; j < 4; ++j) acc[i][j] = (f32x4_t){0.f, 0.f, 0.f, 0.f};

    const int srow = lane >> 2;
    const int scol = (lane & 3) * 8;
    const unsigned short* Ag0 = A + (size_t)(bm + w * 16 + srow) * lda + scol;
    const unsigned short* Ag1 = A + (size_t)(bm + 64 + w * 16 + srow) * lda + scol;
    const unsigned short* Bg0 = B + (size_t)(bn + w * 16 + srow) * ldb + scol;
    const unsigned short* Bg1 = B + (size_t)(bn + 64 + w * 16 + srow) * ldb + scol;
    unsigned short* la0 = &As[(w * 16) * 32];
    unsigned short* la1 = &As[(64 + w * 16) * 32];
    unsigned short* lb0 = &Bs[(w * 16) * 32];
    unsigned short* lb1 = &Bs[(64 + w * 16) * 32];

    const int fr = lane & 15;
    const int fk = (lane >> 4) * 8;

    for (int k0 = 0; k0 < K; k0 += 32) {
        __syncthreads();
        __builtin_amdgcn_global_load_lds((const AS1 void*)(Ag0 + k0), (AS3 void*)la0, 16, 0, 0);
        __builtin_amdgcn_global_load_lds((const AS1 void*)(Ag1 + k0), (AS3 void*)la1, 16, 0, 0);
        __builtin_amdgcn_global_load_lds((const AS1 void*)(Bg0 + k0), (AS3 void*)lb0, 16, 0, 0);
        __builtin_amdgcn_global_load_lds((const AS1 void*)(Bg1 + k0), (AS3 void*)lb1, 16, 0, 0);
        __syncthreads();

        bf16x8_t af[4], bfr[4];
#pragma unroll
        for (int i = 0; i < 4; ++i)
            af[i] = *(const bf16x8_t*)&As[(wm + i * 16 + fr) * 32 + fk];
#pragma unroll
        for (int j = 0; j < 4; ++j)
            bfr[j] = *(const bf16x8_t*)&Bs[(wn + j * 16 + fr) * 32 + fk];
#pragma unroll
        for (int i = 0; i < 4; ++i)
#pragma unroll
            for (int j = 0; j < 4; ++j)
                acc[i][j] = __builtin_amdgcn_mfma_f32_16x16x32_bf16(
                    af[i], bfr[j], acc[i][j], 0, 0, 0);
    }

    const int erow = (lane >> 4) * 4;
    const int ecol = lane & 15;
#pragma unroll
    for (int i = 0; i < 4; ++i) {
        int gr0 = bm + wm + i * 16 + erow;
#pragma unroll
        for (int j = 0; j < 4; ++j) {
            int gc = bn + wn + j * 16 + ecol;
#pragma unroll
            for (int r = 0; r < 4; ++r) {
                float v = acc[i][j][r];
                if (act == 1) {
                    float t = v + bias[gr0 + r];
                    v = (t > 20.f) ? t : log1pf(__expf(t));
                } else if (act == 2) {
                    v = v / (1.f + __expf(-v));
                }
                C[(size_t)(gr0 + r) * ldc + gc] = v;
            }
        }
    }
}

// ---------------------------------------------------------------------------
// causal depthwise conv (k=4) + bias + silu on [d][m] layout, bf16 output.
// ---------------------------------------------------------------------------
__global__ __launch_bounds__(256) void conv_silu_kernel(
    const float* __restrict__ xT,     // [2048][8192] fp32
    const float* __restrict__ w,      // [2048][4]
    const float* __restrict__ bias,   // [2048]
    unsigned short* __restrict__ xcT16) // [2048][8192] bf16
{
    int gid = blockIdx.x * blockDim.x + threadIdx.x;  // 0 .. 2048*2048-1
    int d = gid >> 11;
    int c4 = gid & 2047;
    int m0 = c4 * 4;
    int l0 = m0 & (L_SEQ - 1);

    const float* row = xT + (size_t)d * BL;
    float4 v = *(const float4*)(row + m0);
    float4 p;
    if (l0 == 0) { p.x = p.y = p.z = p.w = 0.f; }
    else         { p = *(const float4*)(row + m0 - 4); }

    float4 wv = ((const float4*)w)[d];
    float bb = bias[d];
    float e[4];
    e[0] = bb + wv.x * p.y + wv.y * p.z + wv.z * p.w + wv.w * v.x;
    e[1] = bb + wv.x * p.z + wv.y * p.w + wv.z * v.x + wv.w * v.y;
    e[2] = bb + wv.x * p.w + wv.y * v.x + wv.z * v.y + wv.w * v.z;
    e[3] = bb + wv.x * v.x + wv.y * v.y + wv.z * v.z + wv.w * v.w;
    ushort4 o;
    o.x = f2bf(e[0] / (1.f + __expf(-e[0])));
    o.y = f2bf(e[1] / (1.f + __expf(-e[1])));
    o.z = f2bf(e[2] / (1.f + __expf(-e[2])));
    o.w = f2bf(e[3] / (1.f + __expf(-e[3])));
    ((ushort4*)(xcT16 + (size_t)d * BL))[c4] = o;
}

// ---------------------------------------------------------------------------
// 32x32 tiled transposes (coalesced both sides)
// ---------------------------------------------------------------------------
__global__ __launch_bounds__(256) void transpose_f32_bf16(
    const float* __restrict__ in, int ldin,
    unsigned short* __restrict__ out, int ldout)
{
    __shared__ float tl[32][33];
    int r0 = blockIdx.y * 32, c0 = blockIdx.x * 32;
    int tx = threadIdx.x & 31, ty = threadIdx.x >> 5;
#pragma unroll
    for (int k = 0; k < 4; ++k)
        tl[ty + 8 * k][tx] = in[(size_t)(r0 + ty + 8 * k) * ldin + c0 + tx];
    __syncthreads();
#pragma unroll
    for (int k = 0; k < 4; ++k)
        out[(size_t)(c0 + ty + 8 * k) * ldout + r0 + tx] = f2bf(tl[tx][ty + 8 * k]);
}

__global__ __launch_bounds__(256) void transpose_bf16(
    const unsigned short* __restrict__ in, int ldin,
    unsigned short* __restrict__ out, int ldout)
{
    __shared__ unsigned short tl[32][33];
    int r0 = blockIdx.y * 32, c0 = blockIdx.x * 32;
    int tx = threadIdx.x & 31, ty = threadIdx.x >> 5;
#pragma unroll
    for (int k = 0; k < 4; ++k)
        tl[ty + 8 * k][tx] = in[(size_t)(r0 + ty + 8 * k) * ldin + c0 + tx];
    __syncthreads();
#pragma unroll
    for (int k = 0; k < 4; ++k)
        out[(size_t)(c0 + ty + 8 * k) * ldout + r0 + tx] = tl[tx][ty + 8 * k];
}

// ---------------------------------------------------------------------------
// Single-pass selective scan: ONE WAVE per (b,d) sequence.
//   R3 post-mortem: VALUBusy pinned at 77%; WRITE_SIZE tripled (partial-line
//   scattered y stores); issued-op accounting shows addressing + unpack
//   overhead rivals core math. R4 changes (numerically identical):
//     - SADDR B/C loads: uint32 element offset off uniform base -> compiler
//       emits global_load with SGPR base + small voffset/imm, killing the
//       per-load 64-bit VGPR address arithmetic.
//     - dt*x premultiplied once at staging into s_dtx (inner loop drops all
//       x unpacks + 1 mul/step).
//     - y staged in s_y; chunk-end bulk store: lane reads 2xfloat4 from LDS,
//       multiplies by z (regs, loaded coalesced at chunk start), stores
//       2x global_store_dwordx4. Full-line writes only.
//   Fold network unchanged (verified): 15 blended folds + xor2/xor1
//   butterfly per 16 steps; writer lanes (lane&3)==0 hold step (lane>>2)&15.
// ---------------------------------------------------------------------------
#define SCHUNK 512

#define GROUP16(BC, CC, BN, CN, GG)                                          \
{                                                                            \
    _Pragma("unroll")                                                        \
    for (int t = 0; t < 16; ++t) {      /* prefetch next group (saddr) */    \
        BN[t] = xb[bo + t * 256u];                                           \
        CN[t] = xb[bo + t * 256u + 64u];                                     \
    }                                                                        \
    bo += 16u * 256u;                                                        \
    float4 dta = *(const float4*)&sdt[(GG)];                                 \
    float4 dtb = *(const float4*)&sdt[(GG) + 4];                             \
    float4 dtc = *(const float4*)&sdt[(GG) + 8];                             \
    float4 dtd = *(const float4*)&sdt[(GG) + 12];                            \
    float4 dxa = *(const float4*)&sdtx[(GG)];                                \
    float4 dxb = *(const float4*)&sdtx[(GG) + 4];                            \
    float4 dxc = *(const float4*)&sdtx[(GG) + 8];                            \
    float4 dxd = *(const float4*)&sdtx[(GG) + 12];                           \
    float dt16[16] = {dta.x, dta.y, dta.z, dta.w, dtb.x, dtb.y, dtb.z, dtb.w,\
                      dtc.x, dtc.y, dtc.z, dtc.w, dtd.x, dtd.y, dtd.z, dtd.w};\
    float dx16[16] = {dxa.x, dxa.y, dxa.z, dxa.w, dxb.x, dxb.y, dxb.z, dxb.w,\
                      dxc.x, dxc.y, dxc.z, dxc.w, dxd.x, dxd.y, dxd.z, dxd.w};\
    float pr[16];                                                            \
    _Pragma("unroll")                                                        \
    for (int t = 0; t < 16; ++t) {                                           \
        float a = __builtin_amdgcn_exp2f(dt16[t] * An2);                     \
        h = fmaf(h, a, dx16[t] * BC[t]);                                     \
        pr[t] = h * CC[t];                                                   \
    }                                                                        \
    _Pragma("unroll")                                                        \
    for (int t = 0; t < 8; ++t) {       /* fold xor32: 16 -> 8 */            \
        float send = (lane & 32) ? pr[t] : pr[t + 8];                        \
        float recv = __shfl_xor(send, 32);                                   \
        pr[t] = ((lane & 32) ? pr[t + 8] : pr[t]) + recv;                    \
    }                                                                        \
    _Pragma("unroll")                                                        \
    for (int t = 0; t < 4; ++t) {       /* fold xor16: 8 -> 4 */             \
        float send = (lane & 16) ? pr[t] : pr[t + 4];                        \
        float recv = __shfl_xor(send, 16);                                   \
        pr[t] = ((lane & 16) ? pr[t + 4] : pr[t]) + recv;                    \
    }                                                                        \
    _Pragma("unroll")                                                        \
    for (int t = 0; t < 2; ++t) {       /* fold xor8: 4 -> 2 */              \
        float send = (lane & 8) ? pr[t] : pr[t + 2];                         \
        float recv = __shfl_xor(send, 8);                                    \
        pr[t] = ((lane & 8) ? pr[t + 2] : pr[t]) + recv;                     \
    }                                                                        \
    {                                   /* fold xor4: 2 -> 1 */              \
        float send = (lane & 4) ? pr[0] : pr[1];                             \
        float recv = __shfl_xor(send, 4);                                    \
        pr[0] = ((lane & 4) ? pr[1] : pr[0]) + recv;                         \
    }                                                                        \
    pr[0] += __shfl_xor(pr[0], 2);      /* butterfly over 4 n-residues */    \
    pr[0] += __shfl_xor(pr[0], 1);                                           \
    if ((lane & 3) == 0) {              /* 16 writer lanes -> LDS (pre-z) */ \
        int t0 = (GG) + myt16;                                               \
        float xv = bf2f(sx[t0]);                                             \
        sy[t0] = fmaf(Dd, xv, pr[0]);                                        \
    }                                                                        \
}

__global__ __launch_bounds__(256, 4) void scan_seq_kernel(
    const float* __restrict__ dtT,           // [2048][8192] fp32
    const unsigned short* __restrict__ xcT16,// [2048][8192] bf16
    const float* __restrict__ xdbl,          // [8192+16][256] fp32 (B@+128, C@+192)
    float* __restrict__ zyT,                 // [2048][8192]: silu(z) in, y out
    const float* __restrict__ A_log,         // [2048][64]
    const float* __restrict__ Dp)            // [2048]
{
    __shared__ __align__(16) float s_dt[4][SCHUNK];           // 8 KB
    __shared__ __align__(16) float s_dtx[4][SCHUNK];          // 8 KB
    __shared__ __align__(16) unsigned short s_x[4][SCHUNK];   // 4 KB
    __shared__ __align__(16) float s_y[4][SCHUNK];            // 8 KB
    // 28 KB/block; grid gives 4 blocks/CU (16 waves/CU)

    const int tid  = threadIdx.x;
    const int wid  = tid >> 6;
    const int lane = tid & 63;
    const int bi   = blockIdx.x;            // 0..1023
    const int b    = bi & 1;                // XCD-friendly: same-b per XCD
    const int d    = (bi >> 1) * 4 + wid;

    const size_t rowbase = (size_t)d * BL + (size_t)b * L_SEQ;
    const float An2 = -__expf(A_log[d * D_STATE + lane]) * 1.44269504f;
    const float Dd  = Dp[d];

    float* sdt = s_dt[wid];
    float* sdtx = s_dtx[wid];
    unsigned short* sx = s_x[wid];
    float* sy = s_y[wid];
    const float* dtrow = dtT + rowbase;
    const unsigned short* xrow = xcT16 + rowbase;
    float* zrow = zyT + rowbase;
    const int myt16 = (lane >> 2) & 15;     // step index this lane ends up with

    // prefetch chunk 0: dt 2x float4 (elems lane*4, 256+lane*4),
    //                   x  2x ushort4 (same element ranges)
    float4 pA = ((const float4*)dtrow)[lane];
    float4 pB = ((const float4*)dtrow)[lane + 64];
    ushort4 pX0 = ((const ushort4*)xrow)[lane];
    ushort4 pX1 = ((const ushort4*)xrow)[lane + 64];

    // rolling B/C prefetch via 32-bit element offset off the uniform base
    // (saddr form). Pad-safe past the end: xdbl has ~1 MiB of slack.
    const float* __restrict__ xb = xdbl;
    unsigned bo = (unsigned)(b * L_SEQ) * 256u + DT_RANK + (unsigned)lane;
    float Bv0[16], Cv0[16], Bv1[16], Cv1[16];
#pragma unroll
    for (int t = 0; t < 16; ++t) { Bv0[t] = xb[bo + t * 256u]; Cv0[t] = xb[bo + t * 256u + 64u]; }
    bo += 16u * 256u;

    float h = 0.f;

    for (int c = 0; c < L_SEQ / SCHUNK; ++c) {
        // z for the CURRENT chunk -> regs (consumed at chunk end; 512 steps
        // of latency cover)
        float4 z0 = ((const float4*)(zrow + c * SCHUNK))[lane];
        float4 z1 = ((const float4*)(zrow + c * SCHUNK))[lane + 64];

        // stage current chunk to this wave's private LDS slice (no barrier:
        // intra-wave LDS ops are processed in order)
        ((float4*)sdt)[lane]      = pA;
        ((float4*)sdt)[lane + 64] = pB;
        ((ushort4*)sx)[lane]      = pX0;
        ((ushort4*)sx)[lane + 64] = pX1;
        float4 dxA, dxB;
        dxA.x = pA.x * bf2f(pX0.x); dxA.y = pA.y * bf2f(pX0.y);
        dxA.z = pA.z * bf2f(pX0.z); dxA.w = pA.w * bf2f(pX0.w);
        dxB.x = pB.x * bf2f(pX1.x); dxB.y = pB.y * bf2f(pX1.y);
        dxB.z = pB.z * bf2f(pX1.z); dxB.w = pB.w * bf2f(pX1.w);
        ((float4*)sdtx)[lane]      = dxA;
        ((float4*)sdtx)[lane + 64] = dxB;

        if (c < L_SEQ / SCHUNK - 1) {       // register-prefetch next chunk
            pA  = ((const float4*)(dtrow + (c + 1) * SCHUNK))[lane];
            pB  = ((const float4*)(dtrow + (c + 1) * SCHUNK))[lane + 64];
            pX0 = ((const ushort4*)(xrow + (c + 1) * SCHUNK))[lane];
            pX1 = ((const ushort4*)(xrow + (c + 1) * SCHUNK))[lane + 64];
        }
        const int cbase = c * SCHUNK;

        for (int g = 0; g < SCHUNK; g += 32) {
            GROUP16(Bv0, Cv0, Bv1, Cv1, g);
            GROUP16(Bv1, Cv1, Bv0, Cv0, g + 16);
        }

        // chunk end: y = s_y * z, coalesced full-line stores
        float4 y0 = ((const float4*)sy)[lane];
        float4 y1 = ((const float4*)sy)[lane + 64];
        y0.x *= z0.x; y0.y *= z0.y; y0.z *= z0.z; y0.w *= z0.w;
        y1.x *= z1.x; y1.y *= z1.y; y1.z *= z1.z; y1.w *= z1.w;
        ((float4*)(zrow + cbase))[lane]      = y0;
        ((float4*)(zrow + cbase))[lane + 64] = y1;
    }
}

// ---------------------------------------------------------------------------
extern "C" void kernel_launch(void* const* d_in, const int* in_sizes, int n_in,
                              void* d_out, int out_size, void* d_ws, size_t ws_size,
                              hipStream_t stream)
{
    const float* hs        = (const float*)d_in[0];  // [8192][1024]
    const float* in_proj_w = (const float*)d_in[1];  // [4096][1024]
    const float* conv_w    = (const float*)d_in[2];  // [2048][4]
    const float* conv_b    = (const float*)d_in[3];  // [2048]
    const float* x_proj_w  = (const float*)d_in[4];  // [256][2048]
    const float* dt_proj_w = (const float*)d_in[5];  // [2048][128]
    const float* dt_proj_b = (const float*)d_in[6];  // [2048]
    const float* A_log     = (const float*)d_in[7];  // [2048][64]
    const float* Dp        = (const float*)d_in[8];  // [2048]
    const float* out_proj_w= (const float*)d_in[9];  // [1024][2048]
    float* out = (float*)d_out;                      // [8192][1024]

    // workspace map (MiB offsets; peak ~177.5 MiB):
    //  S0 @0   : xT fp32 (64) -> xc16 bf16 (32) @0 -> dtT fp32 (64) @0
    //  S1 @64  : zT fp32 (64)  (scan writes y in place)
    //  S2 @128 : W1_16 (8)@128 + hs16 (16)@136 -> xcT16 bf16 (32)@128 -> y16 (32)@128
    //  tail    : xdbl fp32 (8+pad)@160, xdbl16 (2)@169, Wx16 (1)@171,
    //            Wdt16 (.5)@172, Wo16 (4)@173  (end 177)
    char* ws = (char*)d_ws;
    const size_t MiB = 1024 * 1024;
    float*          xT    = (float*)(ws);
    unsigned short* xc16  = (unsigned short*)(ws);
    float*          dtT   = (float*)(ws);
    float*          zT    = (float*)(ws + 64 * MiB);
    unsigned short* W1_16 = (unsigned short*)(ws + 128 * MiB);
    unsigned short* hs16  = (unsigned short*)(ws + 136 * MiB);
    unsigned short* xcT16 = (unsigned short*)(ws + 128 * MiB);
    unsigned short* y16   = (unsigned short*)(ws + 128 * MiB);
    float*          xdbl  = (float*)(ws + 160 * MiB);   // 8 MiB + >=16-row pad
    unsigned short* xdbl16= (unsigned short*)(ws + 169 * MiB);
    unsigned short* Wx16  = (unsigned short*)(ws + 171 * MiB);
    unsigned short* Wdt16 = (unsigned short*)(ws + 172 * MiB);
    unsigned short* Wo16  = (unsigned short*)(ws + 173 * MiB);

    dim3 blk(256);

    // bf16 conversions
    cvt_f32_bf16<<<8192, blk, 0, stream>>>(hs, hs16, 2097152);
    cvt_f32_bf16<<<4096, blk, 0, stream>>>(in_proj_w, W1_16, 1048576);
    cvt_f32_bf16<<<512, blk, 0, stream>>>(x_proj_w, Wx16, 131072);
    cvt_f32_bf16<<<256, blk, 0, stream>>>(dt_proj_w, Wdt16, 65536);
    cvt_f32_bf16<<<2048, blk, 0, stream>>>(out_proj_w, Wo16, 524288);

    // 1) xT[d][m] = W1x . hs^T   (M=2048, N=8192, K=1024)
    gemm_bf16<<<dim3(64, 16), blk, 0, stream>>>(
        W1_16, D_MODEL, hs16, D_MODEL, xT, BL, D_MODEL, nullptr, 0);

    // 2) zT[d][m] = silu(W1z . hs^T)
    gemm_bf16<<<dim3(64, 16), blk, 0, stream>>>(
        W1_16 + (size_t)D_INNER * D_MODEL, D_MODEL, hs16, D_MODEL,
        zT, BL, D_MODEL, nullptr, 2);

    // 3) xcT16 = bf16(silu(conv(xT) + b))
    conv_silu_kernel<<<(D_INNER * (BL / 4)) / 256, blk, 0, stream>>>(
        xT, conv_w, conv_b, xcT16);

    // 4) xc16[m][d] = transpose(xcT16)
    transpose_bf16<<<dim3(BL / 32, D_INNER / 32), blk, 0, stream>>>(
        xcT16, BL, xc16, D_INNER);

    // 5) xdbl[m][256] = xc . x_proj^T   (M=8192, N=256, K=2048)
    gemm_bf16<<<dim3(2, 64), blk, 0, stream>>>(
        xc16, D_INNER, Wx16, D_INNER, xdbl, 256, D_INNER, nullptr, 0);

    // 6) xdbl16 = bf16(xdbl[:, :128])
    cvt_dtpart<<<1024, blk, 0, stream>>>(xdbl, xdbl16);

    // 7) dtT[d][m] = softplus(Wdt . xdbl_dt^T + b[d])  (M=2048, N=8192, K=128)
    gemm_bf16<<<dim3(64, 16), blk, 0, stream>>>(
        Wdt16, DT_RANK, xdbl16, DT_RANK, dtT, BL, DT_RANK, dt_proj_b, 1);

    // 8) single-pass scan: 1 wave per (b,d), y in place over zT
    scan_seq_kernel<<<(B_SZ * D_INNER) / 4, blk, 0, stream>>>(
        dtT, xcT16, xdbl, zT, A_log, Dp);

    // 9) y16[m][d] = bf16(transpose(zT))
    transpose_f32_bf16<<<dim3(BL / 32, D_INNER / 32), blk, 0, stream>>>(
        zT, BL, y16, D_INNER);

    // 10) out = y . out_proj^T   (M=8192, N=1024, K=2048)
    gemm_bf16<<<dim3(8, 64), blk, 0, stream>>>(
        y16, D_INNER, Wo16, D_INNER, out, D_MODEL, D_INNER, nullptr, 0);
}